// Round 4
// baseline (97.769 us; speedup 1.0000x reference)
//
#include <hip/hip_runtime.h>
#include <cstdint>
#include <cstddef>

#define BATCH  8
#define SEQ    4096
#define CHN    256        // channels (OUT)
#define NQ     768        // 3*OUT
#define KTOT   512        // WIN*IN
#define S_B    64         // seq rows per GEMM block
#define TS     128        // scan chunk length
#define NCHUNK (SEQ/TS)   // 32

#define WPL    4128       // bytes per g-plane slice in LDS (256n*16B + 32 pad)
#define WBUF   (4*WPL)    // 16512 bytes per t-step buffer half

typedef __attribute__((ext_vector_type(8))) __bf16    bf16x8;
typedef __attribute__((ext_vector_type(4))) __bf16    bf16x4;
typedef __attribute__((ext_vector_type(4))) float     f32x4;
typedef __attribute__((ext_vector_type(4))) _Float16  f16x4;
typedef __attribute__((ext_vector_type(2))) _Float16  f16x2;

// ---------------------------------------------------------------------------
// K0: convert W (fp32 [768][512]) into frag-major bf16 tiles:
//     Wt[(t*4+g)*768 + n][j] = bf16(W[n][t*32 + g*8 + j]),  t<16, g<4, j<8
// ---------------------------------------------------------------------------
__global__ __launch_bounds__(256) void k_convW(const float* __restrict__ W,
                                               __bf16* __restrict__ Wt) {
    int lin = blockIdx.x * 256 + threadIdx.x;   // 0 .. 49151  (= 64*768)
    int n  = lin % NQ;
    int tg = lin / NQ;                          // t*4+g, 0..63
    const float* src = W + (size_t)n * KTOT + tg * 8;
    float4 a = *(const float4*)(src);
    float4 b = *(const float4*)(src + 4);
    bf16x8 h;
    h[0]=(__bf16)a.x; h[1]=(__bf16)a.y; h[2]=(__bf16)a.z; h[3]=(__bf16)a.w;
    h[4]=(__bf16)b.x; h[5]=(__bf16)b.y; h[6]=(__bf16)b.z; h[7]=(__bf16)b.w;
    *(bf16x8*)(Wt + (size_t)lin * 8) = h;
}

__device__ __forceinline__ float fast_sigmoid(float y) {
    float e = __expf(-y);
    return __builtin_amdgcn_rcpf(1.f + e);
}
__device__ __forceinline__ float fast_tanh(float y) {
    float e = __expf(-2.f * y);
    return __builtin_amdgcn_rcpf(1.f + e) * 2.f - 1.f;
}

// ---------------------------------------------------------------------------
// K1: GEMM (transposed: y^T = W * xw^T) + activations.
// Block = 256 thr = 4 waves; n-slice = 256 (ONE gate, block-uniform);
// wave wn owns n in [64*wn, 64*wn+64); block s-extent 64.
// Per t-step: stage 16 KB of Wt (4 planes, wave wn stages plane g=wn) into
// double-buffered LDS via global_load_lds; one __syncthreads per t.
// LDS = 33.28 KB (As) + 2*16.5 KB (W) = 64.8 KB -> 2 blocks/CU (overlap!).
// Grid = 3 gates * 8 bi * 64 sc = 1536 blocks.
// ---------------------------------------------------------------------------
__global__ __launch_bounds__(256, 2) void k_gemm(
    const float* __restrict__ x, const __bf16* __restrict__ Wt,
    const float* __restrict__ bias,
    _Float16* __restrict__ Zb, _Float16* __restrict__ Fb, _Float16* __restrict__ Ob)
{
    __shared__ char As_b[(S_B + 1) * 512];      // 33280 B, rows s0-1..s0+63, swizzled
    __shared__ char Wl_b[2][WBUF];              // 2 x 16512 B

    int tid = threadIdx.x;
    int bid = blockIdx.x;
    int nsl  = bid % 3;          // gate: 0:z 1:f 2:o
    int rest = bid / 3;
    int bi = rest >> 6;
    int sc = rest & 63;
    int s0 = sc * S_B;
    int wn  = tid >> 6;          // 0..3 : n-sub-slice [64*wn, +64)
    int l   = tid & 63;
    int l15 = l & 15, lg = l >> 4;

    // ---- stage x window (fp32 -> bf16), swizzle byte ^= (row&7)<<4 ----
    #pragma unroll
    for (int i = 0; i < 17; ++i) {
        int idx = tid + i * 256;
        if (idx < (S_B + 1) * 64) {
            int r  = idx >> 6, cg = idx & 63;
            int srow = s0 - 1 + r;
            float4 v = make_float4(0.f, 0.f, 0.f, 0.f);
            if (srow >= 0)
                v = *(const float4*)(x + ((size_t)bi * SEQ + srow) * CHN + cg * 4);
            bf16x4 h;
            h[0]=(__bf16)v.x; h[1]=(__bf16)v.y; h[2]=(__bf16)v.z; h[3]=(__bf16)v.w;
            int boff = (r * 512 + cg * 8) ^ ((r & 7) << 4);
            *(bf16x4*)(As_b + boff) = h;
        }
    }

    // ---- Wt stage: per t, 4 plane-slices of 4 KB; wave wn stages plane g=wn.
    // global elem: Wt[((t*4+g)*768 + nsl*256 + c*64 + l) * 8 .. +8)
    // LDS: Wl_b[buf] + g*WPL + c*1024 (+ lane*16 by HW)
    const __bf16* wt_lane = Wt + ((size_t)nsl * 256 + l) * 8;
    #define STAGE_W(bufi, t)                                                     \
        {                                                                        \
            _Pragma("unroll")                                                    \
            for (int c = 0; c < 4; ++c) {                                        \
                const __bf16* gsrc = wt_lane +                                   \
                    ((size_t)((t) * 4 + wn) * NQ + c * 64) * 8;                  \
                char* ldst = Wl_b[bufi] + wn * WPL + c * 1024;                   \
                __builtin_amdgcn_global_load_lds(                                \
                    (const __attribute__((address_space(1))) void*)gsrc,         \
                    (__attribute__((address_space(3))) void*)ldst, 16, 0, 0);    \
            }                                                                    \
        }

    STAGE_W(0, 0);
    __syncthreads();   // x window + Wt[t=0] ready

    f32x4 acc[4][4];
    const f32x4 vzero = {0.f, 0.f, 0.f, 0.f};
    #pragma unroll
    for (int a = 0; a < 4; ++a)
        #pragma unroll
        for (int b = 0; b < 4; ++b)
            acc[a][b] = vzero;

    // ---- K loop: 16 t-steps of K=32; double-buffered Wt, 1 barrier per t ----
    #pragma unroll
    for (int t = 0; t < 16; ++t) {
        if (t < 15) STAGE_W((t + 1) & 1, t + 1);

        int kh  = t >> 3;            // 0: x[s-1], 1: x[s]
        int kc0 = (t & 7) * 32;
        bf16x8 xf[4];
        #pragma unroll
        for (int st = 0; st < 4; ++st) {
            int row  = st * 16 + l15 + kh;
            int boff = (row * 512 + kc0 * 2 + lg * 16) ^ ((row & 7) << 4);
            xf[st] = *(const bf16x8*)(As_b + boff);
        }
        bf16x8 wf[4];
        #pragma unroll
        for (int nt = 0; nt < 4; ++nt)
            wf[nt] = *(const bf16x8*)(Wl_b[t & 1] + lg * WPL +
                                      (wn * 64 + nt * 16 + l15) * 16);

        __builtin_amdgcn_s_setprio(1);
        #pragma unroll
        for (int nt = 0; nt < 4; ++nt)
            #pragma unroll
            for (int st = 0; st < 4; ++st)
                acc[nt][st] = __builtin_amdgcn_mfma_f32_16x16x32_bf16(
                                  wf[nt], xf[st], acc[nt][st], 0, 0, 0);
        __builtin_amdgcn_s_setprio(0);

        if (t < 15) __syncthreads();   // Wt[t+1] landed; t's ds_reads retired
    }

    // ---- epilogue: gate block-uniform; lane owns 4 consecutive channels ----
    _Float16* buf = (nsl == 0) ? Zb : (nsl == 1) ? Fb : Ob;
    bool is_tanh = (nsl == 0);
    #pragma unroll
    for (int nt = 0; nt < 4; ++nt) {
        int chn = wn * 64 + nt * 16 + lg * 4;    // channel base (0..255)
        float4 bv = *(const float4*)(bias + nsl * 256 + chn);
        #pragma unroll
        for (int st = 0; st < 4; ++st) {
            int s = s0 + st * 16 + l15;
            f16x4 h;
            #pragma unroll
            for (int r = 0; r < 4; ++r) {
                float bvr = (r == 0) ? bv.x : (r == 1) ? bv.y : (r == 2) ? bv.z : bv.w;
                float y = acc[nt][st][r] + bvr;
                float v = is_tanh ? fast_tanh(y) : fast_sigmoid(y);
                h[r] = (_Float16)v;
            }
            *(f16x4*)(buf + ((size_t)bi * SEQ + s) * CHN + chn) = h;
        }
    }
}

// ---------------------------------------------------------------------------
// K2: per-chunk scan summaries; thread handles 2 channels (4B f16x2 loads).
// ---------------------------------------------------------------------------
__global__ __launch_bounds__(128) void k_scan1(const _Float16* __restrict__ Fb,
                                               const _Float16* __restrict__ Zb,
                                               float* __restrict__ Aq,
                                               float* __restrict__ Bq) {
    int bi = blockIdx.x >> 5;
    int ck = blockIdx.x & 31;
    int c2 = threadIdx.x;                       // channel pair 0..127
    size_t base = (((size_t)bi * SEQ + ck * TS) * CHN + c2 * 2) >> 1;
    const f16x2* F2 = (const f16x2*)Fb;
    const f16x2* Z2 = (const f16x2*)Zb;
    float a0 = 1.f, a1 = 1.f, c0 = 0.f, c1 = 0.f;
    #pragma unroll 8
    for (int s = 0; s < TS; ++s) {
        f16x2 f = F2[base + (size_t)s * (CHN / 2)];
        f16x2 z = Z2[base + (size_t)s * (CHN / 2)];
        float f0 = (float)f[0], f1 = (float)f[1];
        c0 = f0 * c0 + (1.f - f0) * (float)z[0];
        c1 = f1 * c1 + (1.f - f1) * (float)z[1];
        a0 *= f0; a1 *= f1;
    }
    int o = blockIdx.x * CHN + c2 * 2;
    *(float2*)(Aq + o) = make_float2(a0, a1);
    *(float2*)(Bq + o) = make_float2(c0, c1);
}

// ---------------------------------------------------------------------------
// K3: sequential carry across chunks. 8 blocks x 256 threads, 32 steps.
// ---------------------------------------------------------------------------
__global__ __launch_bounds__(256) void k_scan2(const float* __restrict__ Aq,
                                               const float* __restrict__ Bq,
                                               float* __restrict__ Cq) {
    int bi = blockIdx.x;
    int ch = threadIdx.x;
    float c = 0.f;
    #pragma unroll
    for (int ck = 0; ck < NCHUNK; ++ck) {
        int o = (bi * NCHUNK + ck) * CHN + ch;
        Cq[o] = c;
        c = Aq[o] * c + Bq[o];
    }
}

// ---------------------------------------------------------------------------
// K4: final pass — redo local scan seeded with carry, out = sigmoid(o) * c.
// ---------------------------------------------------------------------------
__global__ __launch_bounds__(128) void k_scan3(const _Float16* __restrict__ Fb,
                                               const _Float16* __restrict__ Zb,
                                               const _Float16* __restrict__ Ob,
                                               const float* __restrict__ Cq,
                                               float* __restrict__ out) {
    int bi = blockIdx.x >> 5;
    int ck = blockIdx.x & 31;
    int c2 = threadIdx.x;
    float2 c = *(const float2*)(Cq + blockIdx.x * CHN + c2 * 2);
    size_t base = (((size_t)bi * SEQ + ck * TS) * CHN + c2 * 2) >> 1;
    const f16x2* F2 = (const f16x2*)Fb;
    const f16x2* Z2 = (const f16x2*)Zb;
    const f16x2* O2 = (const f16x2*)Ob;
    float* outp = out + (((size_t)bi * SEQ + ck * TS) * CHN + c2 * 2);
    #pragma unroll 4
    for (int s = 0; s < TS; ++s) {
        f16x2 f  = F2[base + (size_t)s * (CHN / 2)];
        f16x2 z  = Z2[base + (size_t)s * (CHN / 2)];
        f16x2 so = O2[base + (size_t)s * (CHN / 2)];
        float f0 = (float)f[0], f1 = (float)f[1];
        c.x = f0 * c.x + (1.f - f0) * (float)z[0];
        c.y = f1 * c.y + (1.f - f1) * (float)z[1];
        *(float2*)(outp + (size_t)s * CHN) = make_float2((float)so[0] * c.x,
                                                         (float)so[1] * c.y);
    }
}

// ---------------------------------------------------------------------------
extern "C" void kernel_launch(void* const* d_in, const int* in_sizes, int n_in,
                              void* d_out, int out_size, void* d_ws, size_t ws_size,
                              hipStream_t stream)
{
    const float* x = (const float*)d_in[0];   // (8,4096,256) fp32
    const float* W = (const float*)d_in[1];   // (768,512)    fp32
    const float* b = (const float*)d_in[2];   // (768,)       fp32
    float* out = (float*)d_out;               // (8,4096,256) fp32

    char* ws = (char*)d_ws;
    const size_t MB = 1024 * 1024;
    _Float16* Zb = (_Float16*)(ws +  0 * MB);   // 16 MB
    _Float16* Fb = (_Float16*)(ws + 16 * MB);   // 16 MB
    _Float16* Ob = (_Float16*)(ws + 32 * MB);   // 16 MB
    __bf16*   Wt = (__bf16*)  (ws + 48 * MB);   // 768 KB
    float*    Aq = (float*)   (ws + 49 * MB);   // 256 KB
    float*    Bq = (float*)   (ws + 50 * MB);   // 256 KB
    float*    Cq = (float*)   (ws + 51 * MB);   // 256 KB

    k_convW<<<dim3(192),            dim3(256), 0, stream>>>(W, Wt);
    k_gemm <<<dim3(3 * BATCH * 64), dim3(256), 0, stream>>>(x, Wt, b, Zb, Fb, Ob);
    k_scan1<<<dim3(BATCH * NCHUNK), dim3(128), 0, stream>>>(Fb, Zb, Aq, Bq);
    k_scan2<<<dim3(BATCH),          dim3(256), 0, stream>>>(Aq, Bq, Cq);
    k_scan3<<<dim3(BATCH * NCHUNK), dim3(128), 0, stream>>>(Fb, Zb, Ob, Cq, out);
}

// Round 5
// 74.023 us; speedup vs baseline: 1.3208x; 1.3208x over previous
//
#include <hip/hip_runtime.h>
#include <cstdint>
#include <cstddef>

#define BATCH  8
#define SEQ    4096
#define CHN    256        // channels (OUT)
#define NQ     768        // 3*OUT
#define KTOT   512        // WIN*IN
#define S_B    64         // seq rows per GEMM block
#define TS     128        // scan chunk length
#define NCHUNK (SEQ/TS)   // 32

typedef __attribute__((ext_vector_type(8))) __bf16    bf16x8;
typedef __attribute__((ext_vector_type(4))) __bf16    bf16x4;
typedef __attribute__((ext_vector_type(4))) float     f32x4;
typedef __attribute__((ext_vector_type(4))) _Float16  f16x4;
typedef __attribute__((ext_vector_type(2))) _Float16  f16x2;

// ---------------------------------------------------------------------------
// K0: convert W (fp32 [768][512]) into frag-major bf16 tiles:
//     Wt[(t*4+g)*768 + n][j] = bf16(W[n][t*32 + g*8 + j]),  t<16, g<4, j<8
// ---------------------------------------------------------------------------
__global__ __launch_bounds__(256) void k_convW(const float* __restrict__ W,
                                               __bf16* __restrict__ Wt) {
    int lin = blockIdx.x * 256 + threadIdx.x;   // 0 .. 49151  (= 64*768)
    int n  = lin % NQ;
    int tg = lin / NQ;                          // t*4+g, 0..63
    const float* src = W + (size_t)n * KTOT + tg * 8;
    float4 a = *(const float4*)(src);
    float4 b = *(const float4*)(src + 4);
    bf16x8 h;
    h[0]=(__bf16)a.x; h[1]=(__bf16)a.y; h[2]=(__bf16)a.z; h[3]=(__bf16)a.w;
    h[4]=(__bf16)b.x; h[5]=(__bf16)b.y; h[6]=(__bf16)b.z; h[7]=(__bf16)b.w;
    *(bf16x8*)(Wt + (size_t)lin * 8) = h;
}

__device__ __forceinline__ float fast_sigmoid(float y) {
    float e = __expf(-y);
    return __builtin_amdgcn_rcpf(1.f + e);
}
__device__ __forceinline__ float fast_tanh(float y) {
    float e = __expf(-2.f * y);
    return __builtin_amdgcn_rcpf(1.f + e) * 2.f - 1.f;
}

// ---------------------------------------------------------------------------
// K1: GEMM (transposed: y^T = W * xw^T) + activations.
// Block = 768 thr = 12 waves; wave wid owns n in [64*wid, 64*wid+64).
// W fragments stream PER-WAVE from L2 (no LDS, no K-loop barriers) with a
// 2-deep register pipeline (8 outstanding 1KB loads/wave). As (x window) is
// the only LDS use; one barrier total. Grid = 8 bi * 64 sc = 512 blocks.
// Unified regs ~150 <= 170 (launch_bounds 768,3) -> 3 waves/SIMD, 1 block/CU.
// ---------------------------------------------------------------------------
__global__ __launch_bounds__(768, 3) void k_gemm(
    const float* __restrict__ x, const __bf16* __restrict__ Wt,
    const float* __restrict__ bias,
    _Float16* __restrict__ Zb, _Float16* __restrict__ Fb, _Float16* __restrict__ Ob)
{
    __shared__ char As_b[(S_B + 1) * 512];      // 33280 B, rows s0-1..s0+63, swizzled

    int tid = threadIdx.x;
    int bi  = blockIdx.x >> 6;
    int sc  = blockIdx.x & 63;
    int s0  = sc * S_B;
    int wid = tid >> 6;          // 0..11 : n-slice [64*wid, +64)
    int l   = tid & 63;
    int l15 = l & 15, lg = l >> 4;

    // ---- stage x window (fp32 -> bf16), swizzle byte ^= (row&7)<<4 ----
    #pragma unroll
    for (int i = 0; i < 6; ++i) {
        int idx = tid + i * 768;
        if (idx < (S_B + 1) * 64) {
            int r  = idx >> 6, cg = idx & 63;
            int srow = s0 - 1 + r;
            float4 v = make_float4(0.f, 0.f, 0.f, 0.f);
            if (srow >= 0)
                v = *(const float4*)(x + ((size_t)bi * SEQ + srow) * CHN + cg * 4);
            bf16x4 h;
            h[0]=(__bf16)v.x; h[1]=(__bf16)v.y; h[2]=(__bf16)v.z; h[3]=(__bf16)v.w;
            int boff = (r * 512 + cg * 8) ^ ((r & 7) << 4);
            *(bf16x4*)(As_b + boff) = h;
        }
    }

    // W fragment base for this lane: elem ((lg*768) + wid*64 + l15) * 8.
    // Per t advance 4*768*8 = 24576 elems; per nt advance 16*8 = 128 elems.
    const __bf16* wp = Wt + ((size_t)lg * NQ + wid * 64 + l15) * 8;
    #define LOADW(dst, t)                                                        \
        {                                                                        \
            _Pragma("unroll")                                                    \
            for (int nt = 0; nt < 4; ++nt)                                       \
                dst[nt] = *(const bf16x8*)(wp + (size_t)(t) * 24576 + nt * 128); \
        }

    bf16x8 wf0[4], wf1[4], wf2[4];
    LOADW(wf0, 0);
    LOADW(wf1, 1);

    f32x4 acc[4][4];
    const f32x4 vzero = {0.f, 0.f, 0.f, 0.f};
    #pragma unroll
    for (int a = 0; a < 4; ++a)
        #pragma unroll
        for (int b = 0; b < 4; ++b)
            acc[a][b] = vzero;

    __syncthreads();   // x window ready (W loads ride on, no barrier needed)

    // ---- K loop: 16 t-steps of K=32; zero barriers, 2-deep W pipeline ----
    #pragma unroll
    for (int t = 0; t < 16; ++t) {
        if (t < 14) LOADW(wf2, t + 2);

        int kh  = t >> 3;            // 0: x[s-1], 1: x[s]
        int kc0 = (t & 7) * 32;
        bf16x8 xf[4];
        #pragma unroll
        for (int st = 0; st < 4; ++st) {
            int row  = st * 16 + l15 + kh;
            int boff = (row * 512 + kc0 * 2 + lg * 16) ^ ((row & 7) << 4);
            xf[st] = *(const bf16x8*)(As_b + boff);
        }

        __builtin_amdgcn_s_setprio(1);
        #pragma unroll
        for (int nt = 0; nt < 4; ++nt)
            #pragma unroll
            for (int st = 0; st < 4; ++st)
                acc[nt][st] = __builtin_amdgcn_mfma_f32_16x16x32_bf16(
                                  wf0[nt], xf[st], acc[nt][st], 0, 0, 0);
        __builtin_amdgcn_s_setprio(0);

        #pragma unroll
        for (int nt = 0; nt < 4; ++nt) { wf0[nt] = wf1[nt]; wf1[nt] = wf2[nt]; }
    }

    // ---- epilogue: wave-uniform gate; lane owns 4 consecutive channels ----
    int gate = wid >> 2;                       // 0:z 1:f 2:o
    _Float16* buf = (gate == 0) ? Zb : (gate == 1) ? Fb : Ob;
    bool is_tanh = (gate == 0);
    #pragma unroll
    for (int nt = 0; nt < 4; ++nt) {
        int n4  = wid * 64 + nt * 16 + lg * 4;   // global n (0..767)
        int chn = n4 & 255;
        float4 bv = *(const float4*)(bias + n4);
        #pragma unroll
        for (int st = 0; st < 4; ++st) {
            int s = s0 + st * 16 + l15;
            f16x4 h;
            #pragma unroll
            for (int r = 0; r < 4; ++r) {
                float bvr = (r == 0) ? bv.x : (r == 1) ? bv.y : (r == 2) ? bv.z : bv.w;
                float y = acc[nt][st][r] + bvr;
                float v = is_tanh ? fast_tanh(y) : fast_sigmoid(y);
                h[r] = (_Float16)v;
            }
            *(f16x4*)(buf + ((size_t)bi * SEQ + s) * CHN + chn) = h;
        }
    }
}

// ---------------------------------------------------------------------------
// K2: per-chunk scan summaries; thread handles 2 channels (4B f16x2 loads).
// ---------------------------------------------------------------------------
__global__ __launch_bounds__(128) void k_scan1(const _Float16* __restrict__ Fb,
                                               const _Float16* __restrict__ Zb,
                                               float* __restrict__ Aq,
                                               float* __restrict__ Bq) {
    int bi = blockIdx.x >> 5;
    int ck = blockIdx.x & 31;
    int c2 = threadIdx.x;                       // channel pair 0..127
    size_t base = (((size_t)bi * SEQ + ck * TS) * CHN + c2 * 2) >> 1;
    const f16x2* F2 = (const f16x2*)Fb;
    const f16x2* Z2 = (const f16x2*)Zb;
    float a0 = 1.f, a1 = 1.f, c0 = 0.f, c1 = 0.f;
    #pragma unroll 8
    for (int s = 0; s < TS; ++s) {
        f16x2 f = F2[base + (size_t)s * (CHN / 2)];
        f16x2 z = Z2[base + (size_t)s * (CHN / 2)];
        float f0 = (float)f[0], f1 = (float)f[1];
        c0 = f0 * c0 + (1.f - f0) * (float)z[0];
        c1 = f1 * c1 + (1.f - f1) * (float)z[1];
        a0 *= f0; a1 *= f1;
    }
    int o = blockIdx.x * CHN + c2 * 2;
    *(float2*)(Aq + o) = make_float2(a0, a1);
    *(float2*)(Bq + o) = make_float2(c0, c1);
}

// ---------------------------------------------------------------------------
// K3: sequential carry across chunks. 8 blocks x 256 threads, 32 steps.
// ---------------------------------------------------------------------------
__global__ __launch_bounds__(256) void k_scan2(const float* __restrict__ Aq,
                                               const float* __restrict__ Bq,
                                               float* __restrict__ Cq) {
    int bi = blockIdx.x;
    int ch = threadIdx.x;
    float c = 0.f;
    #pragma unroll
    for (int ck = 0; ck < NCHUNK; ++ck) {
        int o = (bi * NCHUNK + ck) * CHN + ch;
        Cq[o] = c;
        c = Aq[o] * c + Bq[o];
    }
}

// ---------------------------------------------------------------------------
// K4: final pass — redo local scan seeded with carry, out = sigmoid(o) * c.
// ---------------------------------------------------------------------------
__global__ __launch_bounds__(128) void k_scan3(const _Float16* __restrict__ Fb,
                                               const _Float16* __restrict__ Zb,
                                               const _Float16* __restrict__ Ob,
                                               const float* __restrict__ Cq,
                                               float* __restrict__ out) {
    int bi = blockIdx.x >> 5;
    int ck = blockIdx.x & 31;
    int c2 = threadIdx.x;
    float2 c = *(const float2*)(Cq + blockIdx.x * CHN + c2 * 2);
    size_t base = (((size_t)bi * SEQ + ck * TS) * CHN + c2 * 2) >> 1;
    const f16x2* F2 = (const f16x2*)Fb;
    const f16x2* Z2 = (const f16x2*)Zb;
    const f16x2* O2 = (const f16x2*)Ob;
    float* outp = out + (((size_t)bi * SEQ + ck * TS) * CHN + c2 * 2);
    #pragma unroll 4
    for (int s = 0; s < TS; ++s) {
        f16x2 f  = F2[base + (size_t)s * (CHN / 2)];
        f16x2 z  = Z2[base + (size_t)s * (CHN / 2)];
        f16x2 so = O2[base + (size_t)s * (CHN / 2)];
        float f0 = (float)f[0], f1 = (float)f[1];
        c.x = f0 * c.x + (1.f - f0) * (float)z[0];
        c.y = f1 * c.y + (1.f - f1) * (float)z[1];
        *(float2*)(outp + (size_t)s * CHN) = make_float2((float)so[0] * c.x,
                                                         (float)so[1] * c.y);
    }
}

// ---------------------------------------------------------------------------
extern "C" void kernel_launch(void* const* d_in, const int* in_sizes, int n_in,
                              void* d_out, int out_size, void* d_ws, size_t ws_size,
                              hipStream_t stream)
{
    const float* x = (const float*)d_in[0];   // (8,4096,256) fp32
    const float* W = (const float*)d_in[1];   // (768,512)    fp32
    const float* b = (const float*)d_in[2];   // (768,)       fp32
    float* out = (float*)d_out;               // (8,4096,256) fp32

    char* ws = (char*)d_ws;
    const size_t MB = 1024 * 1024;
    _Float16* Zb = (_Float16*)(ws +  0 * MB);   // 16 MB
    _Float16* Fb = (_Float16*)(ws + 16 * MB);   // 16 MB
    _Float16* Ob = (_Float16*)(ws + 32 * MB);   // 16 MB
    __bf16*   Wt = (__bf16*)  (ws + 48 * MB);   // 768 KB
    float*    Aq = (float*)   (ws + 49 * MB);   // 256 KB
    float*    Bq = (float*)   (ws + 50 * MB);   // 256 KB
    float*    Cq = (float*)   (ws + 51 * MB);   // 256 KB

    k_convW<<<dim3(192),            dim3(256), 0, stream>>>(W, Wt);
    k_gemm <<<dim3(BATCH * 64),     dim3(768), 0, stream>>>(x, Wt, b, Zb, Fb, Ob);
    k_scan1<<<dim3(BATCH * NCHUNK), dim3(128), 0, stream>>>(Fb, Zb, Aq, Bq);
    k_scan2<<<dim3(BATCH),          dim3(256), 0, stream>>>(Aq, Bq, Cq);
    k_scan3<<<dim3(BATCH * NCHUNK), dim3(128), 0, stream>>>(Fb, Zb, Ob, Cq, out);
}